// Round 7
// baseline (1706.588 us; speedup 1.0000x reference)
//
#include <hip/hip_runtime.h>
#include <hip/hip_bf16.h>

typedef __attribute__((ext_vector_type(8))) short bf16x8;
typedef __attribute__((ext_vector_type(4))) float f32x4;

#define MFMA __builtin_amdgcn_mfma_f32_16x16x32_bf16

// ---------- helpers ----------
__device__ __forceinline__ short f2bf(float f) {
    union { __hip_bfloat16 h; short s; } u;
    u.h = __float2bfloat16(f);
    return u.s;
}

__device__ __forceinline__ void gld_lds16(const void* g, void* l) {
    auto gp = (const __attribute__((address_space(1))) void*)(g);
    auto lp = (__attribute__((address_space(3))) void*)(l);
    __builtin_amdgcn_global_load_lds(gp, lp, 16, 0, 0);
}

// ---------- fp32 [R][C] -> MFMA-fragment-tiled bf16 (no transpose) ----------
// tile (r16, c32): lane l holds (row=l&15, k=(l>>4)*8+j) at tile*1024 + l*16 + j*2
__global__ __launch_bounds__(64) void cvt_tile(const float* __restrict__ in,
                                               __hip_bfloat16* __restrict__ out, int C) {
    const int cd32 = C >> 5;
    const int tile = blockIdx.x;
    const int r16 = tile / cd32, c32 = tile - r16 * cd32;
    const int l = threadIdx.x;
    const int row = (r16 << 4) + (l & 15);
    const int c0 = (c32 << 5) + ((l >> 4) << 3);
    const float* src = in + (size_t)row * C + c0;
    short o[8];
#pragma unroll
    for (int j = 0; j < 8; ++j) o[j] = f2bf(src[j]);
    *(bf16x8*)((char*)out + (size_t)tile * 1024 + (l << 4)) = *(bf16x8*)o;
}

// ---------- fp32 W[K][N] -> fragment-tiled bf16 of W^T (tiles over (n16, k32)) ----------
__global__ __launch_bounds__(64) void tcvt_tile(const float* __restrict__ in,
                                                __hip_bfloat16* __restrict__ out,
                                                int N, int K) {
    const int kd32 = K >> 5;
    const int tile = blockIdx.x;
    const int n16 = tile / kd32, k32 = tile - n16 * kd32;
    const int l = threadIdx.x;
    const int n = (n16 << 4) + (l & 15);
    const int k0 = (k32 << 5) + ((l >> 4) << 3);
    short o[8];
#pragma unroll
    for (int j = 0; j < 8; ++j) o[j] = f2bf(in[(size_t)(k0 + j) * N + n]);
    *(bf16x8*)((char*)out + (size_t)tile * 1024 + (l << 4)) = *(bf16x8*)o;
}

// ---------- per-wave K-split GEMM, A direct-to-VGPR, B via LDS ----------
// 64x64 tile/block, 4 waves each owning a private K-quarter (KC k32-steps).
// A: fragment-tiled global -> 16 NAMED bf16x8 regs (4 rotating slots), coalesced
//    1KB loads. B: fragment-tiled global -> LDS via global_load_lds, 4 bufs x 4KB
//    per wave (64KB block LDS). Uniform 8-op issue groups [4xB-lds + 4xA],
//    sched_barrier-pinned, per-wave counted vmcnt(16)/8/0, NO loop barriers.
// MODE 0: h0   (bf16 fragment-tiled out)
// MODE 1: step (relu(acc + v0*Wi0[c] + v1*Wi1[c]) -> bf16 fragment-tiled out)
// MODE 2: decoder (fp32 out, row r -> t=r>>8, b=r&255 -> out[b][t][p])
template <int MODE, int KC>
__global__ __launch_bounds__(256) void gemm_w(const __hip_bfloat16* __restrict__ A,
                                              const __hip_bfloat16* __restrict__ B,
                                              void* __restrict__ outp,
                                              const float* __restrict__ v,
                                              const float* __restrict__ Wi, int t) {
    constexpr int KD32 = KC * 4;  // K/32 total
    __shared__ __align__(16) char lds[65536];  // 4 waves x 4 bufs x 4KB
    const int id = blockIdx.x;
    int bm, bn;
    if constexpr (MODE == 2) {
        int xcd = id & 7, idx = id >> 3;
        int sw = xcd * 400 + idx;
        bm = sw >> 3;
        bn = sw & 7;
    } else {
        int xcd = id & 7, j = id >> 3;
        bn = (xcd << 3) + (j & 7);
        bm = j >> 3;
    }
    const int tid = threadIdx.x, wv = tid >> 6, lane = tid & 63;
    char* myl = lds + (wv << 14);  // 16KB per wave
    const int kw0 = wv * KC;
    const int bm4 = bm << 2, bn4 = bn << 2;

    constexpr size_t FSTR = (size_t)KD32 << 10;  // fragment-row stride (bytes)
    const char* pA = (const char*)A + (((size_t)(bm4 * KD32 + kw0)) << 10) + (lane << 4);
    const char* pB = (const char*)B + (((size_t)(bn4 * KD32 + kw0)) << 10) + (lane << 4);

    f32x4 acc[4][4] = {};
    bf16x8 A00, A01, A02, A03, A10, A11, A12, A13,
           A20, A21, A22, A23, A30, A31, A32, A33;

#define STAGEB(SLOT, KI)                                   \
    do {                                                   \
        const char* pb_ = pB + ((size_t)(KI) << 10);       \
        char* d_ = myl + ((SLOT) << 12);                   \
        gld_lds16(pb_, d_);                                \
        gld_lds16(pb_ + FSTR, d_ + 1024);                  \
        gld_lds16(pb_ + 2 * FSTR, d_ + 2048);              \
        gld_lds16(pb_ + 3 * FSTR, d_ + 3072);              \
    } while (0)

#define LOADA(S, KI)                                       \
    do {                                                   \
        const char* pa_ = pA + ((size_t)(KI) << 10);       \
        A##S##0 = *(const bf16x8*)(pa_);                   \
        A##S##1 = *(const bf16x8*)(pa_ + FSTR);            \
        A##S##2 = *(const bf16x8*)(pa_ + 2 * FSTR);        \
        A##S##3 = *(const bf16x8*)(pa_ + 3 * FSTR);        \
    } while (0)

#define COMPUTE(S)                                                    \
    do {                                                              \
        const char* bb_ = myl + ((S) << 12) + (lane << 4);            \
        bf16x8 b0 = *(const bf16x8*)(bb_);                            \
        bf16x8 b1 = *(const bf16x8*)(bb_ + 1024);                     \
        bf16x8 b2 = *(const bf16x8*)(bb_ + 2048);                     \
        bf16x8 b3 = *(const bf16x8*)(bb_ + 3072);                     \
        acc[0][0] = MFMA(A##S##0, b0, acc[0][0], 0, 0, 0);            \
        acc[0][1] = MFMA(A##S##0, b1, acc[0][1], 0, 0, 0);            \
        acc[0][2] = MFMA(A##S##0, b2, acc[0][2], 0, 0, 0);            \
        acc[0][3] = MFMA(A##S##0, b3, acc[0][3], 0, 0, 0);            \
        acc[1][0] = MFMA(A##S##1, b0, acc[1][0], 0, 0, 0);            \
        acc[1][1] = MFMA(A##S##1, b1, acc[1][1], 0, 0, 0);            \
        acc[1][2] = MFMA(A##S##1, b2, acc[1][2], 0, 0, 0);            \
        acc[1][3] = MFMA(A##S##1, b3, acc[1][3], 0, 0, 0);            \
        acc[2][0] = MFMA(A##S##2, b0, acc[2][0], 0, 0, 0);            \
        acc[2][1] = MFMA(A##S##2, b1, acc[2][1], 0, 0, 0);            \
        acc[2][2] = MFMA(A##S##2, b2, acc[2][2], 0, 0, 0);            \
        acc[2][3] = MFMA(A##S##2, b3, acc[2][3], 0, 0, 0);            \
        acc[3][0] = MFMA(A##S##3, b0, acc[3][0], 0, 0, 0);            \
        acc[3][1] = MFMA(A##S##3, b1, acc[3][1], 0, 0, 0);            \
        acc[3][2] = MFMA(A##S##3, b2, acc[3][2], 0, 0, 0);            \
        acc[3][3] = MFMA(A##S##3, b3, acc[3][3], 0, 0, 0);            \
    } while (0)

// drain to VM (group KI done), issue group KI+3 into slot SP, compute slot S
#define ITER(S, SP, VM, DOISS, KI)                                 \
    do {                                                           \
        asm volatile("s_waitcnt vmcnt(%0)" ::"i"(VM) : "memory");  \
        __builtin_amdgcn_sched_barrier(0);                         \
        if (DOISS) {                                               \
            STAGEB(SP, (KI) + 3);                                  \
            LOADA(SP, (KI) + 3);                                   \
        }                                                          \
        __builtin_amdgcn_sched_barrier(0);                         \
        COMPUTE(S);                                                \
    } while (0)

    // prologue: 3 pinned uniform groups [4xB-lds + 4xA]
    STAGEB(0, 0); LOADA(0, 0);
    __builtin_amdgcn_sched_barrier(0);
    STAGEB(1, 1); LOADA(1, 1);
    __builtin_amdgcn_sched_barrier(0);
    STAGEB(2, 2); LOADA(2, 2);
    __builtin_amdgcn_sched_barrier(0);

    int s = 0;
    for (; s + 4 < KC; s += 4) {
        ITER(0, 3, 16, true, s + 0);
        ITER(1, 0, 16, true, s + 1);
        ITER(2, 1, 16, true, s + 2);
        ITER(3, 2, 16, true, s + 3);
    }
    // tail (s == KC-4)
    ITER(0, 3, 16, true,  s + 0);   // stages group KC-1
    ITER(1, 0, 16, false, s + 1);
    ITER(2, 1, 8,  false, s + 2);
    ITER(3, 2, 0,  false, s + 3);

#undef ITER
#undef COMPUTE
#undef LOADA
#undef STAGEB

    // ---- cross-wave K-reduction via LDS (reuse own 16KB region) ----
#pragma unroll
    for (int f = 0; f < 4; ++f)
#pragma unroll
        for (int g = 0; g < 4; ++g)
            *(f32x4*)(myl + (((f << 2) + g) << 10) + (lane << 4)) = acc[f][g];
    __syncthreads();
    f32x4 fin[4];
#pragma unroll
    for (int g = 0; g < 4; ++g) {
        f32x4 s0 = *(const f32x4*)(lds + (0 << 14) + (((wv << 2) + g) << 10) + (lane << 4));
        f32x4 s1 = *(const f32x4*)(lds + (1 << 14) + (((wv << 2) + g) << 10) + (lane << 4));
        f32x4 s2 = *(const f32x4*)(lds + (2 << 14) + (((wv << 2) + g) << 10) + (lane << 4));
        f32x4 s3 = *(const f32x4*)(lds + (3 << 14) + (((wv << 2) + g) << 10) + (lane << 4));
        fin[g] = (s0 + s1) + (s2 + s3);
    }

    // ---- epilogue: wave wv owns rows [bm*64 + wv*16, +16) ----
    const int rbase = (bm << 6) + (wv << 4) + ((lane >> 4) << 2);
    const int cbase = (bn << 6) + (lane & 15);

    if constexpr (MODE == 0 || MODE == 1) {
        char* O = (char*)outp;  // fragment-tiled
#pragma unroll
        for (int j = 0; j < 4; ++j) {
            int r = rbase + j;
            float v0 = 0.f, v1 = 0.f;
            if constexpr (MODE == 1) {
                v0 = v[(size_t)(r * 100 + t) * 2 + 0];
                v1 = v[(size_t)(r * 100 + t) * 2 + 1];
            }
#pragma unroll
            for (int g = 0; g < 4; ++g) {
                int c = cbase + (g << 4);
                float val = fin[g][j];
                if constexpr (MODE == 1) {
                    val = fmaxf(val + v0 * Wi[c] + v1 * Wi[4096 + c], 0.0f);
                }
                size_t off = ((size_t)(r >> 4) * 128 + (c >> 5)) * 1024 +
                             ((size_t)((r & 15) + (((c >> 3) & 3) << 4)) << 4) +
                             ((c & 7) << 1);
                *(short*)(O + off) = f2bf(val);
            }
        }
    } else {
        float* O = (float*)outp;  // place_preds [256][100][512]
#pragma unroll
        for (int j = 0; j < 4; ++j) {
            int r = rbase + j;
            int tt = r >> 8;
            int b = r & 255;
#pragma unroll
            for (int g = 0; g < 4; ++g) {
                int c = cbase + (g << 4);
                O[((size_t)b * 100 + tt) * 512 + c] = fin[g][j];
            }
        }
    }
}

// ---------- launch ----------
extern "C" void kernel_launch(void* const* d_in, const int* in_sizes, int n_in,
                              void* d_out, int out_size, void* d_ws, size_t ws_size,
                              hipStream_t stream) {
    const float* v     = (const float*)d_in[0];  // [256][100][2]
    const float* P0    = (const float*)d_in[1];  // [256][512]
    const float* W_enc = (const float*)d_in[2];  // [512][4096]
    const float* W_in  = (const float*)d_in[3];  // [2][4096]
    const float* W_rec = (const float*)d_in[4];  // [4096][4096]
    const float* W_dec = (const float*)d_in[5];  // [4096][512]
    float* out = (float*)d_out;                  // [256][100][512]

    char* ws = (char*)d_ws;
    __hip_bfloat16* Wrt = (__hip_bfloat16*)(ws + 0);          // W_rec^T tiled
    __hip_bfloat16* Wet = (__hip_bfloat16*)(ws + 33554432);   // W_enc^T tiled
    __hip_bfloat16* Wdt = (__hip_bfloat16*)(ws + 37748736);   // W_dec^T tiled
    __hip_bfloat16* P0t = (__hip_bfloat16*)(ws + 41943040);   // P0 tiled
    __hip_bfloat16* h0  = (__hip_bfloat16*)(ws + 42205184);   // h0 tiled
    __hip_bfloat16* G   = (__hip_bfloat16*)(ws + 44302336);   // 100 tiled slabs

    tcvt_tile<<<32768, 64, 0, stream>>>(W_rec, Wrt, 4096, 4096);
    tcvt_tile<<<4096, 64, 0, stream>>>(W_enc, Wet, 4096, 512);
    tcvt_tile<<<4096, 64, 0, stream>>>(W_dec, Wdt, 512, 4096);
    cvt_tile<<<256, 64, 0, stream>>>(P0, P0t, 512);

    // h0 = P0 @ W_enc   (K=512 -> KC=4)
    gemm_w<0, 4><<<256, 256, 0, stream>>>(P0t, Wet, (void*)h0, nullptr, nullptr, 0);

    // recurrent steps (K=4096 -> KC=32)
    for (int t = 0; t < 100; ++t) {
        const __hip_bfloat16* hprev = (t == 0) ? h0 : (G + (size_t)(t - 1) * 1048576);
        gemm_w<1, 32><<<256, 256, 0, stream>>>(hprev, Wrt,
                                               (void*)(G + (size_t)t * 1048576), v, W_in, t);
    }

    // decoder: [25600][4096] tiled @ Wdt -> d_out
    gemm_w<2, 32><<<3200, 256, 0, stream>>>(G, Wdt, (void*)out, nullptr, nullptr, 0);
}

// Round 8
// 1666.497 us; speedup vs baseline: 1.0241x; 1.0241x over previous
//
#include <hip/hip_runtime.h>
#include <hip/hip_bf16.h>

typedef __attribute__((ext_vector_type(8))) short bf16x8;
typedef __attribute__((ext_vector_type(4))) float f32x4;

#define MFMA __builtin_amdgcn_mfma_f32_16x16x32_bf16

// ---------- helpers ----------
__device__ __forceinline__ short f2bf(float f) {
    union { __hip_bfloat16 h; short s; } u;
    u.h = __float2bfloat16(f);
    return u.s;
}

__device__ __forceinline__ void gld_lds16(const void* g, void* l) {
    auto gp = (const __attribute__((address_space(1))) void*)(g);
    auto lp = (__attribute__((address_space(3))) void*)(l);
    __builtin_amdgcn_global_load_lds(gp, lp, 16, 0, 0);
}

// ---------- fp32 [R][C] -> MFMA-fragment-tiled bf16 (no transpose) ----------
// tile (r16, c32): lane l holds (row=l&15, k=(l>>4)*8+j) at tile*1024 + l*16 + j*2
__global__ __launch_bounds__(64) void cvt_tile(const float* __restrict__ in,
                                               __hip_bfloat16* __restrict__ out, int C) {
    const int cd32 = C >> 5;
    const int tile = blockIdx.x;
    const int r16 = tile / cd32, c32 = tile - r16 * cd32;
    const int l = threadIdx.x;
    const int row = (r16 << 4) + (l & 15);
    const int c0 = (c32 << 5) + ((l >> 4) << 3);
    const float* src = in + (size_t)row * C + c0;
    short o[8];
#pragma unroll
    for (int j = 0; j < 8; ++j) o[j] = f2bf(src[j]);
    *(bf16x8*)((char*)out + (size_t)tile * 1024 + (l << 4)) = *(bf16x8*)o;
}

// ---------- fp32 W[K][N] -> fragment-tiled bf16 of W^T (tiles over (n16, k32)) ----------
__global__ __launch_bounds__(64) void tcvt_tile(const float* __restrict__ in,
                                                __hip_bfloat16* __restrict__ out,
                                                int N, int K) {
    const int kd32 = K >> 5;
    const int tile = blockIdx.x;
    const int n16 = tile / kd32, k32 = tile - n16 * kd32;
    const int l = threadIdx.x;
    const int n = (n16 << 4) + (l & 15);
    const int k0 = (k32 << 5) + ((l >> 4) << 3);
    short o[8];
#pragma unroll
    for (int j = 0; j < 8; ++j) o[j] = f2bf(in[(size_t)(k0 + j) * N + n]);
    *(bf16x8*)((char*)out + (size_t)tile * 1024 + (l << 4)) = *(bf16x8*)o;
}

// ---------- per-wave K-split GEMM, A direct-to-VGPR, B via LDS ----------
// 64x64 tile/block, NW waves each owning a private K-chunk of KC k32-steps
// (K = NW*KC*32). A: fragment-tiled global -> 16 NAMED bf16x8 regs (4 rotating
// slots). B: fragment-tiled global -> LDS (4 bufs x 4KB per wave). Uniform
// 8-op issue groups [4xB-lds + 4xA], sched_barrier-pinned, per-wave counted
// vmcnt(16)/8/0, NO barriers in the main loop. NW-way LDS reduce at the end.
// MODE 0: h0   (bf16 fragment-tiled out)
// MODE 1: step (relu(acc + v0*Wi0[c] + v1*Wi1[c]) -> bf16 fragment-tiled out)
// MODE 2: decoder (fp32 out, row r -> t=r>>8, b=r&255 -> out[b][t][p])
template <int MODE, int NW, int KC>
__global__ __launch_bounds__(NW * 64) void gemm_w(const __hip_bfloat16* __restrict__ A,
                                                  const __hip_bfloat16* __restrict__ B,
                                                  void* __restrict__ outp,
                                                  const float* __restrict__ v,
                                                  const float* __restrict__ Wi, int t) {
    constexpr int KD32 = KC * NW;           // K/32 total
    __shared__ __align__(16) char lds[NW * 16384];
    const int id = blockIdx.x;
    int bm, bn;
    if constexpr (MODE == 2) {
        int xcd = id & 7, idx = id >> 3;
        int sw = xcd * 400 + idx;
        bm = sw >> 3;
        bn = sw & 7;
    } else {
        int xcd = id & 7, j = id >> 3;
        bn = (xcd << 3) + (j & 7);
        bm = j >> 3;
    }
    const int tid = threadIdx.x, wv = tid >> 6, lane = tid & 63;
    char* myl = lds + (wv << 14);  // 16KB per wave
    const int kw0 = wv * KC;
    const int bm4 = bm << 2, bn4 = bn << 2;

    constexpr size_t FSTR = (size_t)KD32 << 10;  // fragment-row stride (bytes)
    const char* pA = (const char*)A + (((size_t)(bm4 * KD32 + kw0)) << 10) + (lane << 4);
    const char* pB = (const char*)B + (((size_t)(bn4 * KD32 + kw0)) << 10) + (lane << 4);

    f32x4 acc[4][4] = {};
    bf16x8 A00, A01, A02, A03, A10, A11, A12, A13,
           A20, A21, A22, A23, A30, A31, A32, A33;

#define STAGEB(SLOT, KI)                                   \
    do {                                                   \
        const char* pb_ = pB + ((size_t)(KI) << 10);       \
        char* d_ = myl + ((SLOT) << 12);                   \
        gld_lds16(pb_, d_);                                \
        gld_lds16(pb_ + FSTR, d_ + 1024);                  \
        gld_lds16(pb_ + 2 * FSTR, d_ + 2048);              \
        gld_lds16(pb_ + 3 * FSTR, d_ + 3072);              \
    } while (0)

#define LOADA(S, KI)                                       \
    do {                                                   \
        const char* pa_ = pA + ((size_t)(KI) << 10);       \
        A##S##0 = *(const bf16x8*)(pa_);                   \
        A##S##1 = *(const bf16x8*)(pa_ + FSTR);            \
        A##S##2 = *(const bf16x8*)(pa_ + 2 * FSTR);        \
        A##S##3 = *(const bf16x8*)(pa_ + 3 * FSTR);        \
    } while (0)

#define COMPUTE(S)                                                    \
    do {                                                              \
        const char* bb_ = myl + ((S) << 12) + (lane << 4);            \
        bf16x8 b0 = *(const bf16x8*)(bb_);                            \
        bf16x8 b1 = *(const bf16x8*)(bb_ + 1024);                     \
        bf16x8 b2 = *(const bf16x8*)(bb_ + 2048);                     \
        bf16x8 b3 = *(const bf16x8*)(bb_ + 3072);                     \
        acc[0][0] = MFMA(A##S##0, b0, acc[0][0], 0, 0, 0);            \
        acc[0][1] = MFMA(A##S##0, b1, acc[0][1], 0, 0, 0);            \
        acc[0][2] = MFMA(A##S##0, b2, acc[0][2], 0, 0, 0);            \
        acc[0][3] = MFMA(A##S##0, b3, acc[0][3], 0, 0, 0);            \
        acc[1][0] = MFMA(A##S##1, b0, acc[1][0], 0, 0, 0);            \
        acc[1][1] = MFMA(A##S##1, b1, acc[1][1], 0, 0, 0);            \
        acc[1][2] = MFMA(A##S##1, b2, acc[1][2], 0, 0, 0);            \
        acc[1][3] = MFMA(A##S##1, b3, acc[1][3], 0, 0, 0);            \
        acc[2][0] = MFMA(A##S##2, b0, acc[2][0], 0, 0, 0);            \
        acc[2][1] = MFMA(A##S##2, b1, acc[2][1], 0, 0, 0);            \
        acc[2][2] = MFMA(A##S##2, b2, acc[2][2], 0, 0, 0);            \
        acc[2][3] = MFMA(A##S##2, b3, acc[2][3], 0, 0, 0);            \
        acc[3][0] = MFMA(A##S##3, b0, acc[3][0], 0, 0, 0);            \
        acc[3][1] = MFMA(A##S##3, b1, acc[3][1], 0, 0, 0);            \
        acc[3][2] = MFMA(A##S##3, b2, acc[3][2], 0, 0, 0);            \
        acc[3][3] = MFMA(A##S##3, b3, acc[3][3], 0, 0, 0);            \
    } while (0)

#define ITER(S, SP, VM, DOISS, KI)                                 \
    do {                                                           \
        asm volatile("s_waitcnt vmcnt(%0)" ::"i"(VM) : "memory");  \
        __builtin_amdgcn_sched_barrier(0);                         \
        if (DOISS) {                                               \
            STAGEB(SP, (KI) + 3);                                  \
            LOADA(SP, (KI) + 3);                                   \
        }                                                          \
        __builtin_amdgcn_sched_barrier(0);                         \
        COMPUTE(S);                                                \
    } while (0)

    // prologue: 3 pinned uniform groups [4xB-lds + 4xA] = 24 outstanding
    STAGEB(0, 0); LOADA(0, 0);
    __builtin_amdgcn_sched_barrier(0);
    STAGEB(1, 1); LOADA(1, 1);
    __builtin_amdgcn_sched_barrier(0);
    STAGEB(2, 2); LOADA(2, 2);
    __builtin_amdgcn_sched_barrier(0);

    int s = 0;
    for (; s + 4 < KC; s += 4) {
        ITER(0, 3, 16, true, s + 0);
        ITER(1, 0, 16, true, s + 1);
        ITER(2, 1, 16, true, s + 2);
        ITER(3, 2, 16, true, s + 3);
    }
    // tail (s == KC-4)
    ITER(0, 3, 16, true,  s + 0);   // stages group KC-1
    ITER(1, 0, 16, false, s + 1);
    ITER(2, 1, 8,  false, s + 2);
    ITER(3, 2, 0,  false, s + 3);

#undef ITER
#undef COMPUTE
#undef LOADA
#undef STAGEB

    // ---- cross-wave K-reduction via LDS (wave-private 16KB regions) ----
#pragma unroll
    for (int f = 0; f < 4; ++f)
#pragma unroll
        for (int g = 0; g < 4; ++g)
            *(f32x4*)(myl + (((f << 2) + g) << 10) + (lane << 4)) = acc[f][g];
    __syncthreads();

    constexpr int FPW = 16 / NW;  // fragments owned per wave
    f32x4 fin[FPW];
#pragma unroll
    for (int q = 0; q < FPW; ++q) {
        const int fid = wv * FPW + q;
        f32x4 ssum = {};
#pragma unroll
        for (int w = 0; w < NW; ++w)
            ssum += *(const f32x4*)(lds + (w << 14) + (fid << 10) + (lane << 4));
        fin[q] = ssum;
    }

    // ---- epilogue: wave owns fragments fid = wv*FPW + q; f=fid>>2, g=fid&3 ----
    if constexpr (MODE == 0 || MODE == 1) {
        char* O = (char*)outp;  // fragment-tiled
#pragma unroll
        for (int q = 0; q < FPW; ++q) {
            const int fid = wv * FPW + q;
            const int fr = fid >> 2, g = fid & 3;
            const int rbase = (bm << 6) + (fr << 4) + ((lane >> 4) << 2);
            const int c = (bn << 6) + (g << 4) + (lane & 15);
#pragma unroll
            for (int j = 0; j < 4; ++j) {
                int r = rbase + j;
                float val = fin[q][j];
                if constexpr (MODE == 1) {
                    float v0 = v[(size_t)(r * 100 + t) * 2 + 0];
                    float v1 = v[(size_t)(r * 100 + t) * 2 + 1];
                    val = fmaxf(val + v0 * Wi[c] + v1 * Wi[4096 + c], 0.0f);
                }
                size_t off = ((size_t)(r >> 4) * 128 + (c >> 5)) * 1024 +
                             ((size_t)((r & 15) + (((c >> 3) & 3) << 4)) << 4) +
                             ((c & 7) << 1);
                *(short*)(O + off) = f2bf(val);
            }
        }
    } else {
        float* O = (float*)outp;  // place_preds [256][100][512]
#pragma unroll
        for (int q = 0; q < FPW; ++q) {
            const int fid = wv * FPW + q;
            const int fr = fid >> 2, g = fid & 3;
            const int rbase = (bm << 6) + (fr << 4) + ((lane >> 4) << 2);
            const int c = (bn << 6) + (g << 4) + (lane & 15);
#pragma unroll
            for (int j = 0; j < 4; ++j) {
                int r = rbase + j;
                int tt = r >> 8;
                int b = r & 255;
                O[((size_t)b * 100 + tt) * 512 + c] = fin[q][j];
            }
        }
    }
}

// ---------- launch ----------
extern "C" void kernel_launch(void* const* d_in, const int* in_sizes, int n_in,
                              void* d_out, int out_size, void* d_ws, size_t ws_size,
                              hipStream_t stream) {
    const float* v     = (const float*)d_in[0];  // [256][100][2]
    const float* P0    = (const float*)d_in[1];  // [256][512]
    const float* W_enc = (const float*)d_in[2];  // [512][4096]
    const float* W_in  = (const float*)d_in[3];  // [2][4096]
    const float* W_rec = (const float*)d_in[4];  // [4096][4096]
    const float* W_dec = (const float*)d_in[5];  // [4096][512]
    float* out = (float*)d_out;                  // [256][100][512]

    char* ws = (char*)d_ws;
    __hip_bfloat16* Wrt = (__hip_bfloat16*)(ws + 0);          // W_rec^T tiled
    __hip_bfloat16* Wet = (__hip_bfloat16*)(ws + 33554432);   // W_enc^T tiled
    __hip_bfloat16* Wdt = (__hip_bfloat16*)(ws + 37748736);   // W_dec^T tiled
    __hip_bfloat16* P0t = (__hip_bfloat16*)(ws + 41943040);   // P0 tiled
    __hip_bfloat16* h0  = (__hip_bfloat16*)(ws + 42205184);   // h0 tiled
    __hip_bfloat16* G   = (__hip_bfloat16*)(ws + 44302336);   // 100 tiled slabs

    tcvt_tile<<<32768, 64, 0, stream>>>(W_rec, Wrt, 4096, 4096);
    tcvt_tile<<<4096, 64, 0, stream>>>(W_enc, Wet, 4096, 512);
    tcvt_tile<<<4096, 64, 0, stream>>>(W_dec, Wdt, 512, 4096);
    cvt_tile<<<256, 64, 0, stream>>>(P0, P0t, 512);

    // h0 = P0 @ W_enc   (K=512: NW=4, KC=4)
    gemm_w<0, 4, 4><<<256, 256, 0, stream>>>(P0t, Wet, (void*)h0, nullptr, nullptr, 0);

    // recurrent steps (K=4096: NW=8, KC=16 -> 2 waves/SIMD)
    for (int t = 0; t < 100; ++t) {
        const __hip_bfloat16* hprev = (t == 0) ? h0 : (G + (size_t)(t - 1) * 1048576);
        gemm_w<1, 8, 16><<<256, 512, 0, stream>>>(hprev, Wrt,
                                                  (void*)(G + (size_t)t * 1048576), v, W_in, t);
    }

    // decoder: [25600][4096] tiled @ Wdt -> d_out  (NW=8, KC=16)
    gemm_w<2, 8, 16><<<3200, 512, 0, stream>>>(G, Wdt, (void*)out, nullptr, nullptr, 0);
}

// Round 9
// 1511.253 us; speedup vs baseline: 1.1293x; 1.1027x over previous
//
#include <hip/hip_runtime.h>
#include <hip/hip_bf16.h>

typedef __attribute__((ext_vector_type(8))) short bf16x8;
typedef __attribute__((ext_vector_type(4))) float f32x4;

#define MFMA __builtin_amdgcn_mfma_f32_16x16x32_bf16

// ---------- helpers ----------
__device__ __forceinline__ short f2bf(float f) {
    union { __hip_bfloat16 h; short s; } u;
    u.h = __float2bfloat16(f);
    return u.s;
}

// ---------- fp32 [R][C] -> MFMA-fragment-tiled bf16 (no transpose) ----------
// tile (r16, c32): lane l holds (row=l&15, k=(l>>4)*8+j) at tile*1024 + l*16 + j*2
__global__ __launch_bounds__(64) void cvt_tile(const float* __restrict__ in,
                                               __hip_bfloat16* __restrict__ out, int C) {
    const int cd32 = C >> 5;
    const int tile = blockIdx.x;
    const int r16 = tile / cd32, c32 = tile - r16 * cd32;
    const int l = threadIdx.x;
    const int row = (r16 << 4) + (l & 15);
    const int c0 = (c32 << 5) + ((l >> 4) << 3);
    const float* src = in + (size_t)row * C + c0;
    short o[8];
#pragma unroll
    for (int j = 0; j < 8; ++j) o[j] = f2bf(src[j]);
    *(bf16x8*)((char*)out + (size_t)tile * 1024 + (l << 4)) = *(bf16x8*)o;
}

// ---------- fp32 W[K][N] -> fragment-tiled bf16 of W^T, LDS-staged coalesced ----------
// out tile (n16, k32) at (n16*(K/32) + k32)*1024; 64x64 f32 block per CTA.
__global__ __launch_bounds__(256) void tcvt256(const float* __restrict__ in,
                                               __hip_bfloat16* __restrict__ out,
                                               int N, int K) {
    __shared__ float tile[64][65];
    const int r0 = blockIdx.x << 6;  // K offset (rows of W)
    const int c0 = blockIdx.y << 6;  // N offset (cols of W)
    const int tid = threadIdx.x;
    const int row = tid >> 2, cq = tid & 3;
#pragma unroll
    for (int it = 0; it < 4; ++it) {
        int c4 = cq + (it << 2);  // float4 index within 64 cols
        float4 vv = *(const float4*)(in + (size_t)(r0 + row) * N + c0 + (c4 << 2));
        tile[row][(c4 << 2) + 0] = vv.x;
        tile[row][(c4 << 2) + 1] = vv.y;
        tile[row][(c4 << 2) + 2] = vv.z;
        tile[row][(c4 << 2) + 3] = vv.w;
    }
    __syncthreads();
    const int kd32 = K >> 5;
#pragma unroll
    for (int half = 0; half < 2; ++half) {
        int slot = tid + (half << 8);  // 0..511: 8 out-tiles x 64 lanes
        int ti = slot >> 6, l = slot & 63;
        int ci = ti & 3, ri = ti >> 2;  // ci: n16 sub-tile, ri: k32 sub-tile
        short o[8];
#pragma unroll
        for (int j = 0; j < 8; ++j)
            o[j] = f2bf(tile[(ri << 5) + ((l >> 4) << 3) + j][(ci << 4) + (l & 15)]);
        size_t tidx = (size_t)((c0 >> 4) + ci) * kd32 + (r0 >> 5) + ri;
        *(bf16x8*)((char*)out + tidx * 1024 + (l << 4)) = *(bf16x8*)o;
    }
}

// ---------- per-wave K-split GEMM, BOTH operands direct global->VGPR ----------
// 64x64 tile/block, NW waves each owning a private K-chunk of KC k32-steps
// (K = NW*KC*32). A and B fragment-tiled in global; each fragment load is one
// contiguous coalesced 1KB global_load_dwordx4. 4 rotating NAMED reg slots
// (32 bf16x8), 3-deep prefetch. NO LDS / NO barriers / NO manual vmcnt in the
// main loop — compiler inserts exact counted waits for register loads.
// LDS used only for the final NW-way K-reduction.
// MODE 0: h0   (bf16 fragment-tiled out)
// MODE 1: step (relu(acc + v0*Wi0[c] + v1*Wi1[c]) -> bf16 fragment-tiled out)
// MODE 2: decoder (fp32 out, row r -> t=r>>8, b=r&255 -> out[b][t][p])
template <int MODE, int NW, int KC>
__global__ __launch_bounds__(NW * 64) void gemm_r(const __hip_bfloat16* __restrict__ A,
                                                  const __hip_bfloat16* __restrict__ B,
                                                  void* __restrict__ outp,
                                                  const float* __restrict__ v,
                                                  const float* __restrict__ Wi, int t) {
    constexpr int KD32 = KC * NW;  // K/32 total
    __shared__ __align__(16) char lds[NW * 16384];  // reduction only
    const int id = blockIdx.x;
    int bm, bn;
    if constexpr (MODE == 2) {
        int xcd = id & 7, idx = id >> 3;
        int sw = xcd * 400 + idx;
        bm = sw >> 3;
        bn = sw & 7;
    } else {
        int xcd = id & 7, j = id >> 3;
        bn = (xcd << 3) + (j & 7);
        bm = j >> 3;
    }
    const int tid = threadIdx.x, wv = tid >> 6, lane = tid & 63;
    char* myl = lds + (wv << 14);  // 16KB per wave (reduction)
    const int kw0 = wv * KC;
    const int bm4 = bm << 2, bn4 = bn << 2;

    constexpr size_t FSTR = (size_t)KD32 << 10;  // fragment-row stride (bytes)
    const char* pA = (const char*)A + (((size_t)(bm4 * KD32 + kw0)) << 10) + (lane << 4);
    const char* pB = (const char*)B + (((size_t)(bn4 * KD32 + kw0)) << 10) + (lane << 4);

    f32x4 acc[4][4] = {};
    bf16x8 A00, A01, A02, A03, A10, A11, A12, A13,
           A20, A21, A22, A23, A30, A31, A32, A33;
    bf16x8 B00, B01, B02, B03, B10, B11, B12, B13,
           B20, B21, B22, B23, B30, B31, B32, B33;

#define LOADG(S, KI)                                       \
    do {                                                   \
        const char* pa_ = pA + ((size_t)(KI) << 10);       \
        const char* pb_ = pB + ((size_t)(KI) << 10);       \
        A##S##0 = *(const bf16x8*)(pa_);                   \
        A##S##1 = *(const bf16x8*)(pa_ + FSTR);            \
        A##S##2 = *(const bf16x8*)(pa_ + 2 * FSTR);        \
        A##S##3 = *(const bf16x8*)(pa_ + 3 * FSTR);        \
        B##S##0 = *(const bf16x8*)(pb_);                   \
        B##S##1 = *(const bf16x8*)(pb_ + FSTR);            \
        B##S##2 = *(const bf16x8*)(pb_ + 2 * FSTR);        \
        B##S##3 = *(const bf16x8*)(pb_ + 3 * FSTR);        \
    } while (0)

#define COMPUTE(S)                                             \
    do {                                                       \
        acc[0][0] = MFMA(A##S##0, B##S##0, acc[0][0], 0, 0, 0);\
        acc[0][1] = MFMA(A##S##0, B##S##1, acc[0][1], 0, 0, 0);\
        acc[0][2] = MFMA(A##S##0, B##S##2, acc[0][2], 0, 0, 0);\
        acc[0][3] = MFMA(A##S##0, B##S##3, acc[0][3], 0, 0, 0);\
        acc[1][0] = MFMA(A##S##1, B##S##0, acc[1][0], 0, 0, 0);\
        acc[1][1] = MFMA(A##S##1, B##S##1, acc[1][1], 0, 0, 0);\
        acc[1][2] = MFMA(A##S##1, B##S##2, acc[1][2], 0, 0, 0);\
        acc[1][3] = MFMA(A##S##1, B##S##3, acc[1][3], 0, 0, 0);\
        acc[2][0] = MFMA(A##S##2, B##S##0, acc[2][0], 0, 0, 0);\
        acc[2][1] = MFMA(A##S##2, B##S##1, acc[2][1], 0, 0, 0);\
        acc[2][2] = MFMA(A##S##2, B##S##2, acc[2][2], 0, 0, 0);\
        acc[2][3] = MFMA(A##S##2, B##S##3, acc[2][3], 0, 0, 0);\
        acc[3][0] = MFMA(A##S##3, B##S##0, acc[3][0], 0, 0, 0);\
        acc[3][1] = MFMA(A##S##3, B##S##1, acc[3][1], 0, 0, 0);\
        acc[3][2] = MFMA(A##S##3, B##S##2, acc[3][2], 0, 0, 0);\
        acc[3][3] = MFMA(A##S##3, B##S##3, acc[3][3], 0, 0, 0);\
    } while (0)

#define ITER(S, SP, DOISS, KI)                  \
    do {                                        \
        if (DOISS) LOADG(SP, (KI) + 3);         \
        __builtin_amdgcn_sched_barrier(0);      \
        COMPUTE(S);                             \
        __builtin_amdgcn_sched_barrier(0);      \
    } while (0)

    // prologue: 3 prefetched slot-groups
    LOADG(0, 0);
    __builtin_amdgcn_sched_barrier(0);
    LOADG(1, 1);
    __builtin_amdgcn_sched_barrier(0);
    LOADG(2, 2);
    __builtin_amdgcn_sched_barrier(0);

    int s = 0;
    for (; s + 4 < KC; s += 4) {
        ITER(0, 3, true, s + 0);
        ITER(1, 0, true, s + 1);
        ITER(2, 1, true, s + 2);
        ITER(3, 2, true, s + 3);
    }
    // tail (s == KC-4)
    ITER(0, 3, true,  s + 0);  // prefetches group KC-1
    ITER(1, 0, false, s + 1);
    ITER(2, 1, false, s + 2);
    ITER(3, 2, false, s + 3);

#undef ITER
#undef COMPUTE
#undef LOADG

    // ---- cross-wave K-reduction via LDS (wave-private 16KB regions) ----
#pragma unroll
    for (int f = 0; f < 4; ++f)
#pragma unroll
        for (int g = 0; g < 4; ++g)
            *(f32x4*)(myl + (((f << 2) + g) << 10) + (lane << 4)) = acc[f][g];
    __syncthreads();

    constexpr int FPW = 16 / NW;  // fragments owned per wave
    f32x4 fin[FPW];
#pragma unroll
    for (int q = 0; q < FPW; ++q) {
        const int fid = wv * FPW + q;
        f32x4 ssum = {};
#pragma unroll
        for (int w = 0; w < NW; ++w)
            ssum += *(const f32x4*)(lds + (w << 14) + (fid << 10) + (lane << 4));
        fin[q] = ssum;
    }

    // ---- epilogue: wave owns fragments fid = wv*FPW + q; f=fid>>2, g=fid&3 ----
    if constexpr (MODE == 0 || MODE == 1) {
        char* O = (char*)outp;  // fragment-tiled
#pragma unroll
        for (int q = 0; q < FPW; ++q) {
            const int fid = wv * FPW + q;
            const int fr = fid >> 2, g = fid & 3;
            const int rbase = (bm << 6) + (fr << 4) + ((lane >> 4) << 2);
            const int c = (bn << 6) + (g << 4) + (lane & 15);
#pragma unroll
            for (int j = 0; j < 4; ++j) {
                int r = rbase + j;
                float val = fin[q][j];
                if constexpr (MODE == 1) {
                    float v0 = v[(size_t)(r * 100 + t) * 2 + 0];
                    float v1 = v[(size_t)(r * 100 + t) * 2 + 1];
                    val = fmaxf(val + v0 * Wi[c] + v1 * Wi[4096 + c], 0.0f);
                }
                size_t off = ((size_t)(r >> 4) * 128 + (c >> 5)) * 1024 +
                             ((size_t)((r & 15) + (((c >> 3) & 3) << 4)) << 4) +
                             ((c & 7) << 1);
                *(short*)(O + off) = f2bf(val);
            }
        }
    } else {
        float* O = (float*)outp;  // place_preds [256][100][512]
#pragma unroll
        for (int q = 0; q < FPW; ++q) {
            const int fid = wv * FPW + q;
            const int fr = fid >> 2, g = fid & 3;
            const int rbase = (bm << 6) + (fr << 4) + ((lane >> 4) << 2);
            const int c = (bn << 6) + (g << 4) + (lane & 15);
#pragma unroll
            for (int j = 0; j < 4; ++j) {
                int r = rbase + j;
                int tt = r >> 8;
                int b = r & 255;
                O[((size_t)b * 100 + tt) * 512 + c] = fin[q][j];
            }
        }
    }
}

// ---------- launch ----------
extern "C" void kernel_launch(void* const* d_in, const int* in_sizes, int n_in,
                              void* d_out, int out_size, void* d_ws, size_t ws_size,
                              hipStream_t stream) {
    const float* v     = (const float*)d_in[0];  // [256][100][2]
    const float* P0    = (const float*)d_in[1];  // [256][512]
    const float* W_enc = (const float*)d_in[2];  // [512][4096]
    const float* W_in  = (const float*)d_in[3];  // [2][4096]
    const float* W_rec = (const float*)d_in[4];  // [4096][4096]
    const float* W_dec = (const float*)d_in[5];  // [4096][512]
    float* out = (float*)d_out;                  // [256][100][512]

    char* ws = (char*)d_ws;
    __hip_bfloat16* Wrt = (__hip_bfloat16*)(ws + 0);          // W_rec^T tiled
    __hip_bfloat16* Wet = (__hip_bfloat16*)(ws + 33554432);   // W_enc^T tiled
    __hip_bfloat16* Wdt = (__hip_bfloat16*)(ws + 37748736);   // W_dec^T tiled
    __hip_bfloat16* P0t = (__hip_bfloat16*)(ws + 41943040);   // P0 tiled
    __hip_bfloat16* h0  = (__hip_bfloat16*)(ws + 42205184);   // h0 tiled
    __hip_bfloat16* G   = (__hip_bfloat16*)(ws + 44302336);   // 100 tiled slabs

    tcvt256<<<dim3(64, 64), 256, 0, stream>>>(W_rec, Wrt, 4096, 4096);
    tcvt256<<<dim3(8, 64), 256, 0, stream>>>(W_enc, Wet, 4096, 512);
    tcvt256<<<dim3(64, 8), 256, 0, stream>>>(W_dec, Wdt, 512, 4096);
    cvt_tile<<<256, 64, 0, stream>>>(P0, P0t, 512);

    // h0 = P0 @ W_enc   (K=512: NW=4, KC=4)
    gemm_r<0, 4, 4><<<256, 256, 0, stream>>>(P0t, Wet, (void*)h0, nullptr, nullptr, 0);

    // recurrent steps (K=4096: NW=4, KC=32)
    for (int t = 0; t < 100; ++t) {
        const __hip_bfloat16* hprev = (t == 0) ? h0 : (G + (size_t)(t - 1) * 1048576);
        gemm_r<1, 4, 32><<<256, 256, 0, stream>>>(hprev, Wrt,
                                                  (void*)(G + (size_t)t * 1048576), v, W_in, t);
    }

    // decoder: [25600][4096] tiled @ Wdt -> d_out  (NW=4, KC=32)
    gemm_r<2, 4, 32><<<3200, 256, 0, stream>>>(G, Wdt, (void*)out, nullptr, nullptr, 0);
}